// Round 4
// baseline (1329.670 us; speedup 1.0000x reference)
//
#include <hip/hip_runtime.h>
#include <stddef.h>

typedef float f32x4 __attribute__((ext_vector_type(4)));
typedef short s16x8 __attribute__((ext_vector_type(8)));

__device__ __forceinline__ short f2bf(float f) {
    unsigned u = __float_as_uint(f);
    unsigned r = (u + 0x7fffu + ((u >> 16) & 1u)) >> 16;   // RNE
    return (short)r;
}

__device__ __forceinline__ void load_lds16(const void* g, void* l) {
    __builtin_amdgcn_global_load_lds(
        (const __attribute__((address_space(1))) unsigned int*)g,
        (__attribute__((address_space(3))) unsigned int*)l, 16, 0, 0);
}

// ---------------- bf16 MFMA GEMM: C = act(A @ W^T + bias) ------------------
// 128x128 tile, BK=64, 4 waves. Linear LDS + XOR-swizzled global source +
// swizzled ds_read (rule #21). XCD-aware bijective block swizzle (nwg%8==0).
template<bool OBF16, bool RELU>
__global__ __launch_bounds__(256)
void gemm_mfma(const short* __restrict__ A, const short* __restrict__ W,
               const float* __restrict__ bias, void* __restrict__ Cv,
               int M, int N, int K)
{
    __shared__ short As[128 * 64];
    __shared__ short Bs[128 * 64];
    const int tid = threadIdx.x;
    const int l    = tid & 63;
    const int wave = tid >> 6;
    const int wr = wave >> 1, wc = wave & 1;

    // XCD swizzle: contiguous chunks per XCD (all our grids: nwg % 8 == 0)
    const int nwg = gridDim.x * gridDim.y;
    int flat = blockIdx.y * gridDim.x + blockIdx.x;
    flat = (flat & 7) * (nwg >> 3) + (flat >> 3);
    const int n0 = (flat % gridDim.x) * 128;
    const int m0 = (flat / gridDim.x) * 128;

    f32x4 acc[4][4];
#pragma unroll
    for (int i = 0; i < 4; ++i)
#pragma unroll
        for (int j = 0; j < 4; ++j) {
            acc[i][j][0] = 0.f; acc[i][j][1] = 0.f;
            acc[i][j][2] = 0.f; acc[i][j][3] = 0.f;
        }

    const int srow = tid >> 3;
    const int gc   = (tid & 7) ^ (srow & 7);
    const short* gA = A + (size_t)(m0 + srow) * K + gc * 8;
    const short* gB = W + (size_t)(n0 + srow) * K + gc * 8;
    char* AsB = (char*)As;
    char* BsB = (char*)Bs;
    char* dstA = AsB + wave * 1024;
    char* dstB = BsB + wave * 1024;

    int aoff[4], boff[4], soff[2];
#pragma unroll
    for (int mi = 0; mi < 4; ++mi) aoff[mi] = (wr * 64 + mi * 16 + (l & 15)) * 128;
#pragma unroll
    for (int ni = 0; ni < 4; ++ni) boff[ni] = (wc * 64 + ni * 16 + (l & 15)) * 128;
#pragma unroll
    for (int kh = 0; kh < 2; ++kh) soff[kh] = ((kh * 4 + (l >> 4)) ^ (l & 7)) * 16;

    for (int kt = 0; kt < K; kt += 64) {
#pragma unroll
        for (int j = 0; j < 4; ++j) {
            load_lds16(gA + (size_t)j * 32 * K + kt, dstA + j * 4096);
            load_lds16(gB + (size_t)j * 32 * K + kt, dstB + j * 4096);
        }
        __syncthreads();
#pragma unroll
        for (int kh = 0; kh < 2; ++kh) {
            s16x8 af[4], bfr[4];
#pragma unroll
            for (int mi = 0; mi < 4; ++mi)
                af[mi] = *(const s16x8*)(AsB + aoff[mi] + soff[kh]);
#pragma unroll
            for (int ni = 0; ni < 4; ++ni)
                bfr[ni] = *(const s16x8*)(BsB + boff[ni] + soff[kh]);
#pragma unroll
            for (int mi = 0; mi < 4; ++mi)
#pragma unroll
                for (int ni = 0; ni < 4; ++ni)
                    acc[mi][ni] = __builtin_amdgcn_mfma_f32_16x16x32_bf16(
                        af[mi], bfr[ni], acc[mi][ni], 0, 0, 0);
        }
        __syncthreads();
    }

    const int colf = l & 15, rowf = (l >> 4) * 4;
#pragma unroll
    for (int mi = 0; mi < 4; ++mi)
#pragma unroll
        for (int ni = 0; ni < 4; ++ni) {
            const int n = n0 + wc * 64 + ni * 16 + colf;
            const float bv = bias[n];
#pragma unroll
            for (int r = 0; r < 4; ++r) {
                const int m = m0 + wr * 64 + mi * 16 + rowf + r;
                float v = acc[mi][ni][r] + bv;
                if (RELU) v = fmaxf(v, 0.f);
                if (OBF16) ((short*)Cv)[(size_t)m * N + n] = f2bf(v);
                else       ((float*)Cv)[(size_t)m * N + n] = v;
            }
        }
}

// ---------------- f32 -> bf16 conversion (optional elementwise mask) -------
__global__ void conv_bf16(const float* __restrict__ in, const float* __restrict__ mask,
                          short* __restrict__ out, int n4)
{
    int i = blockIdx.x * blockDim.x + threadIdx.x;
    if (i >= n4) return;
    float4 v = ((const float4*)in)[i];
    if (mask) {
        float4 m = ((const float4*)mask)[i];
        v.x *= m.x; v.y *= m.y; v.z *= m.z; v.w *= m.w;
    }
    short4 o;
    o.x = f2bf(v.x); o.y = f2bf(v.y); o.z = f2bf(v.z); o.w = f2bf(v.w);
    ((short4*)out)[i] = o;
}

// ---------------- f32 -> bf16 with K-padding (for GEMM1, 168 -> 192) -------
__global__ void padconv_bf16(const float* __restrict__ in, const float* __restrict__ mask,
                             short* __restrict__ out, int M, int Kin4, int Kout4)
{
    int idx = blockIdx.x * blockDim.x + threadIdx.x;
    if (idx >= M * Kout4) return;
    int m = idx / Kout4, k4 = idx % Kout4;
    float4 v = make_float4(0.f, 0.f, 0.f, 0.f);
    if (k4 < Kin4) {
        v = ((const float4*)in)[(size_t)m * Kin4 + k4];
        if (mask) {
            float4 mm = ((const float4*)mask)[(size_t)m * Kin4 + k4];
            v.x *= mm.x; v.y *= mm.y; v.z *= mm.z; v.w *= mm.w;
        }
    }
    short4 o;
    o.x = f2bf(v.x); o.y = f2bf(v.y); o.z = f2bf(v.z); o.w = f2bf(v.w);
    ((short4*)out)[(size_t)m * Kout4 + k4] = o;
}

// ---------------- combined LSTM biases -------------------------------------
__global__ void bias_sum_kernel(const float* __restrict__ bihf, const float* __restrict__ bhhf,
                                const float* __restrict__ bihb, const float* __restrict__ bhhb,
                                float* __restrict__ o)
{
    int i = blockIdx.x * blockDim.x + threadIdx.x;
    if (i < 2048)      o[i] = bihf[i] + bhhf[i];
    else if (i < 4096) o[i] = bihb[i - 2048] + bhhb[i - 2048];
}

// ---------------- per-direction grid barrier (32 blocks) -------------------
__device__ __forceinline__ void grid_barrier(unsigned* cnt, unsigned* gen, unsigned n)
{
    __threadfence();            // release my stores device-wide
    __syncthreads();
    if (threadIdx.x == 0) {
        unsigned g = __hip_atomic_load(gen, __ATOMIC_RELAXED, __HIP_MEMORY_SCOPE_AGENT);
        unsigned a = __hip_atomic_fetch_add(cnt, 1u, __ATOMIC_ACQ_REL, __HIP_MEMORY_SCOPE_AGENT);
        if (a == n - 1) {
            __hip_atomic_store(cnt, 0u, __ATOMIC_RELAXED, __HIP_MEMORY_SCOPE_AGENT);
            __hip_atomic_fetch_add(gen, 1u, __ATOMIC_RELEASE, __HIP_MEMORY_SCOPE_AGENT);
        } else {
            while (__hip_atomic_load(gen, __ATOMIC_ACQUIRE, __HIP_MEMORY_SCOPE_AGENT) == g)
                __builtin_amdgcn_s_sleep(2);
        }
    }
    __syncthreads();
    __threadfence();            // acquire side: invalidate stale caches
}

// ---------------- persistent BiLSTM: all 64 steps in one launch ------------
// grid = 64 blocks (1/CU): dir = bid>>5, jt = bid&31 (16 gate-cols).
// whh slice (64KB) staged in LDS ONCE; c in registers; h ping-pong in global
// bf16 with per-dir grid barrier between steps.
__global__ __launch_bounds__(256, 1)
void lstm_persistent(const float* __restrict__ xp,   // [2048][4096] f32
                     const short* __restrict__ whb,  // [2][2048][512] bf16
                     short* __restrict__ hbuf,       // [2 dirs][2 bufs][16384] bf16
                     short* __restrict__ y,          // [32][64][1024] bf16
                     float* __restrict__ out,        // hidden/cell at end
                     unsigned* __restrict__ sync)    // [2 dirs][16] cnt@0, gen@8
{
    __shared__ short wS[8 * 64 * 64];    // 64 KB: 8 k-tiles x [64 rows][64 k]
    __shared__ short hT[8 * 32 * 64];    // 32 KB: 8 k-tiles x [32 rows][64 k]
    __shared__ float gbuf[4][32][17];    // 8.7 KB gate exchange

    const int bid = blockIdx.x;
    const int dir = bid >> 5;
    const int jt  = bid & 31;
    const int j0  = jt * 16;
    const int tid = threadIdx.x;
    const int l    = tid & 63;
    const int wave = tid >> 6;

    const short* whh = whb + (size_t)dir * 1048576;
    short* hb = hbuf + dir * 2 * 16384;
    unsigned* cnt = sync + dir * 16;
    unsigned* gen = sync + dir * 16 + 8;

    char* wSB = (char*)wS;
    char* hTB = (char*)hT;

    const int srow = tid >> 3;                    // 0..31
    const int gc   = (tid & 7) ^ (srow & 7);      // pre-swizzled k-chunk

    // ---- stage whh slice into LDS once (8 k-tiles, 2 row-halves each) ----
    {
        const int rt1 = 32 + srow;
        const short* gB0 = whh + (size_t)((srow >> 4) * 512 + j0 + (srow & 15)) * 512 + gc * 8;
        const short* gB1 = whh + (size_t)((rt1 >> 4) * 512 + j0 + (rt1 & 15)) * 512 + gc * 8;
        char* dstW = wSB + wave * 1024;
#pragma unroll
        for (int kt = 0; kt < 8; ++kt) {
            load_lds16(gB0 + kt * 64, dstW + kt * 8192);
            load_lds16(gB1 + kt * 64, dstW + kt * 8192 + 4096);
        }
    }   // first __syncthreads below waits vmcnt(0)

    int soff[2];
    soff[0] = ((0 * 4 + (l >> 4)) ^ (l & 7)) * 16;
    soff[1] = ((1 * 4 + (l >> 4)) ^ (l & 7)) * 16;
    const int a0off = (l & 15) * 128;
    const int a1off = (16 + (l & 15)) * 128;
    const int bof   = (wave * 16 + (l & 15)) * 128;

    const int jl = tid & 15;
    const int bq = tid >> 4;          // 0..15
    char* dstH = hTB + wave * 1024;

    float c0 = 0.f, c1 = 0.f;         // cell state lives in registers

    for (int t = 0; t < 64; ++t) {
        const int tt = dir ? (63 - t) : t;
        const short* hread  = hb + (t & 1) * 16384;
        short*       hwrite = hb + ((t + 1) & 1) * 16384;

        // prefetch xp gate inputs (independent of h -> hides L3 latency)
        const float* xpr0 = xp + ((size_t)(bq * 64 + tt)) * 4096 + dir * 2048 + j0 + jl;
        const float* xpr1 = xp + ((size_t)((bq + 16) * 64 + tt)) * 4096 + dir * 2048 + j0 + jl;
        const float xi0 = xpr0[0], xf0 = xpr0[512], xg0 = xpr0[1024], xo0 = xpr0[1536];
        const float xi1 = xpr1[0], xf1 = xpr1[512], xg1 = xpr1[1024], xo1 = xpr1[1536];

        // stage h[32][512] into LDS (8 k-tiles)
        {
            const short* gA = hread + srow * 512 + gc * 8;
#pragma unroll
            for (int j = 0; j < 8; ++j)
                load_lds16(gA + j * 64, dstH + j * 4096);
        }
        __syncthreads();   // compiler inserts vmcnt(0) before barrier

        // MFMA: gates[32,16] = h @ whh_slice^T, K=512
        f32x4 acc0, acc1;
        acc0[0] = 0.f; acc0[1] = 0.f; acc0[2] = 0.f; acc0[3] = 0.f;
        acc1 = acc0;
#pragma unroll
        for (int kt = 0; kt < 8; ++kt) {
#pragma unroll
            for (int kh = 0; kh < 2; ++kh) {
                s16x8 bv = *(const s16x8*)(wSB + kt * 8192 + bof + soff[kh]);
                s16x8 a0 = *(const s16x8*)(hTB + kt * 4096 + a0off + soff[kh]);
                s16x8 a1 = *(const s16x8*)(hTB + kt * 4096 + a1off + soff[kh]);
                acc0 = __builtin_amdgcn_mfma_f32_16x16x32_bf16(a0, bv, acc0, 0, 0, 0);
                acc1 = __builtin_amdgcn_mfma_f32_16x16x32_bf16(a1, bv, acc1, 0, 0, 0);
            }
        }

        // scatter gates: wave w holds gate w; row = batch, col = j-local
        {
            const int sjl = l & 15, r4 = (l >> 4) * 4;
#pragma unroll
            for (int r = 0; r < 4; ++r) {
                gbuf[wave][r4 + r][sjl]      = acc0[r];
                gbuf[wave][16 + r4 + r][sjl] = acc1[r];
            }
        }
        __syncthreads();

        // fused gate math: thread (bq, jl) owns batches bq and bq+16
        {
            const int j = j0 + jl;
            float g_i = gbuf[0][bq][jl] + xi0;
            float g_f = gbuf[1][bq][jl] + xf0;
            float g_g = gbuf[2][bq][jl] + xg0;
            float g_o = gbuf[3][bq][jl] + xo0;
            float si = 1.f / (1.f + expf(-g_i));
            float sf = 1.f / (1.f + expf(-g_f));
            float so = 1.f / (1.f + expf(-g_o));
            float tg = tanhf(g_g);
            c0 = sf * c0 + si * tg;
            float h0 = so * tanhf(c0);

            g_i = gbuf[0][bq + 16][jl] + xi1;
            g_f = gbuf[1][bq + 16][jl] + xf1;
            g_g = gbuf[2][bq + 16][jl] + xg1;
            g_o = gbuf[3][bq + 16][jl] + xo1;
            si = 1.f / (1.f + expf(-g_i));
            sf = 1.f / (1.f + expf(-g_f));
            so = 1.f / (1.f + expf(-g_o));
            tg = tanhf(g_g);
            c1 = sf * c1 + si * tg;
            float h1 = so * tanhf(c1);

            const short h0b = f2bf(h0), h1b = f2bf(h1);
            hwrite[bq * 512 + j]        = h0b;
            hwrite[(bq + 16) * 512 + j] = h1b;
            y[((size_t)(bq * 64 + tt)) * 1024 + dir * 512 + j]        = h0b;
            y[((size_t)((bq + 16) * 64 + tt)) * 1024 + dir * 512 + j] = h1b;

            if (t == 63) {
                out[524288 + dir * 16384 + bq * 512 + j]                 = h0;
                out[524288 + dir * 16384 + (bq + 16) * 512 + j]          = h1;
                out[524288 + 32768 + dir * 16384 + bq * 512 + j]         = c0;
                out[524288 + 32768 + dir * 16384 + (bq + 16) * 512 + j]  = c1;
            }
        }

        grid_barrier(cnt, gen, 32);
    }
}

// ---------------------------------------------------------------------------
extern "C" void kernel_launch(void* const* d_in, const int* in_sizes, int n_in,
                              void* d_out, int out_size, void* d_ws, size_t ws_size,
                              hipStream_t stream)
{
    const float* x     = (const float*)d_in[0];
    const float* w1    = (const float*)d_in[1];
    const float* b1    = (const float*)d_in[2];
    const float* mask1 = (const float*)d_in[3];
    const float* w2    = (const float*)d_in[4];
    const float* b2    = (const float*)d_in[5];
    const float* mask2 = (const float*)d_in[6];
    const float* wihf  = (const float*)d_in[7];
    const float* whhf  = (const float*)d_in[8];
    const float* bihf  = (const float*)d_in[9];
    const float* bhhf  = (const float*)d_in[10];
    const float* wihb  = (const float*)d_in[11];
    const float* whhb  = (const float*)d_in[12];
    const float* bihb  = (const float*)d_in[13];
    const float* bhhb  = (const float*)d_in[14];
    const float* wo1   = (const float*)d_in[15];
    const float* bo1   = (const float*)d_in[16];
    const float* wo2   = (const float*)d_in[17];
    const float* bo2   = (const float*)d_in[18];
    float* out = (float*)d_out;

    // ---- workspace regions (byte offsets), lifetime-based aliasing ----
    // A @0        : wqb [4096x3584]bf16 (29,360,128) ; later whb [2x2048x512]bf16
    // B @29360128 : h2b [2048x3584]bf16 (14,680,064) ; earlier xpad+w1mb
    // C @44040192 : xp  [2048x4096]f32  (33,554,432) ; earlier w2b
    // D @77594624 : h1b [2048x1792]bf16 ; later ybuf|o1|wo1b|wo2b
    // E @84934656 : hbuf(131072) sync(256) bsum(16384)
    char* base = (char*)d_ws;
    short* wqb  = (short*)base;
    short* whb  = (short*)base;
    char*  Breg = base + 29360128;
    short* h2b  = (short*)Breg;
    short* xpad = (short*)Breg;                       // [2048][192] bf16
    short* w1mb = (short*)(Breg + 786432);            // [1792][192] bf16
    char*  Creg = base + 44040192;
    float* xp   = (float*)Creg;
    short* w2b  = (short*)Creg;
    char*  Dreg = base + 77594624;
    short* h1b  = (short*)Dreg;
    short* ybuf = (short*)Dreg;
    short* o1   = (short*)(Dreg + 4194304);
    short* wo1b = (short*)(Dreg + 5242880);
    short* wo2b = (short*)(Dreg + 5767168);
    char*  Ereg = base + 84934656;
    short* hbuf = (short*)Ereg;
    unsigned* syncp = (unsigned*)(Ereg + 131072);
    float* bsum = (float*)(Ereg + 131328);

    hipMemsetAsync(Ereg, 0, 131328, stream);   // hbuf + sync zeros
    bias_sum_kernel<<<16, 256, 0, stream>>>(bihf, bhhf, bihb, bhhb, bsum);

    // weight / input conversions
    conv_bf16<<<6272, 256, 0, stream>>>(w2, mask2, w2b, 6422528 / 4);
    conv_bf16<<<7168, 256, 0, stream>>>(wihf, nullptr, wqb, 7340032 / 4);
    conv_bf16<<<7168, 256, 0, stream>>>(wihb, nullptr, wqb + 7340032, 7340032 / 4);
    padconv_bf16<<<384, 256, 0, stream>>>(x, nullptr, xpad, 2048, 42, 48);
    padconv_bf16<<<336, 256, 0, stream>>>(w1, mask1, w1mb, 1792, 42, 48);

    // GEMM1 (MFMA, K padded to 192)
    gemm_mfma<true, true><<<dim3(1792 / 128, 2048 / 128), 256, 0, stream>>>(
        xpad, w1mb, b1, h1b, 2048, 1792, 192);

    // GEMM2 (MFMA)
    gemm_mfma<true, true><<<dim3(3584 / 128, 2048 / 128), 256, 0, stream>>>(
        h1b, w2b, b2, h2b, 2048, 3584, 1792);

    // merged LSTM input projection: h2b @ [wihf;wihb]^T + bsum -> xp f32
    gemm_mfma<false, false><<<dim3(4096 / 128, 2048 / 128), 256, 0, stream>>>(
        h2b, wqb, bsum, xp, 2048, 4096, 3584);

    // recurrent weights to bf16 (aliases wqb -> after xproj)
    conv_bf16<<<1024, 256, 0, stream>>>(whhf, nullptr, whb, 1048576 / 4);
    conv_bf16<<<1024, 256, 0, stream>>>(whhb, nullptr, whb + 1048576, 1048576 / 4);
    // head weights to bf16 (alias h1b tail -> after GEMM2)
    conv_bf16<<<256, 256, 0, stream>>>(wo1, nullptr, wo1b, 262144 / 4);
    conv_bf16<<<64, 256, 0, stream>>>(wo2, nullptr, wo2b, 65536 / 4);

    // entire BiLSTM recurrence: ONE persistent kernel, 64 co-resident blocks
    lstm_persistent<<<64, 256, 0, stream>>>(xp, whb, hbuf, ybuf, out, syncp);

    // output head (MFMA)
    gemm_mfma<true, true><<<dim3(256 / 128, 2048 / 128), 256, 0, stream>>>(
        ybuf, wo1b, bo1, o1, 2048, 256, 1024);
    gemm_mfma<false, false><<<dim3(256 / 128, 2048 / 128), 256, 0, stream>>>(
        o1, wo2b, bo2, out, 2048, 256, 256);
}

// Round 5
// 613.827 us; speedup vs baseline: 2.1662x; 2.1662x over previous
//
#include <hip/hip_runtime.h>
#include <stddef.h>

typedef float f32x4 __attribute__((ext_vector_type(4)));
typedef short s16x8 __attribute__((ext_vector_type(8)));

__device__ __forceinline__ short f2bf(float f) {
    unsigned u = __float_as_uint(f);
    unsigned r = (u + 0x7fffu + ((u >> 16) & 1u)) >> 16;   // RNE
    return (short)r;
}

__device__ __forceinline__ void load_lds16(const void* g, void* l) {
    __builtin_amdgcn_global_load_lds(
        (const __attribute__((address_space(1))) unsigned int*)g,
        (__attribute__((address_space(3))) unsigned int*)l, 16, 0, 0);
}

// ---------------- bf16 MFMA GEMM: C = act(A @ W^T + bias) ------------------
// 128x128 tile, BK=64, 4 waves. Linear LDS + XOR-swizzled global source +
// swizzled ds_read (rule #21). XCD-aware bijective block swizzle (nwg%8==0).
template<bool OBF16, bool RELU>
__global__ __launch_bounds__(256)
void gemm_mfma(const short* __restrict__ A, const short* __restrict__ W,
               const float* __restrict__ bias, void* __restrict__ Cv,
               int M, int N, int K)
{
    __shared__ short As[128 * 64];
    __shared__ short Bs[128 * 64];
    const int tid = threadIdx.x;
    const int l    = tid & 63;
    const int wave = tid >> 6;
    const int wr = wave >> 1, wc = wave & 1;

    const int nwg = gridDim.x * gridDim.y;
    int flat = blockIdx.y * gridDim.x + blockIdx.x;
    flat = (flat & 7) * (nwg >> 3) + (flat >> 3);
    const int n0 = (flat % gridDim.x) * 128;
    const int m0 = (flat / gridDim.x) * 128;

    f32x4 acc[4][4];
#pragma unroll
    for (int i = 0; i < 4; ++i)
#pragma unroll
        for (int j = 0; j < 4; ++j) {
            acc[i][j][0] = 0.f; acc[i][j][1] = 0.f;
            acc[i][j][2] = 0.f; acc[i][j][3] = 0.f;
        }

    const int srow = tid >> 3;
    const int gc   = (tid & 7) ^ (srow & 7);
    const short* gA = A + (size_t)(m0 + srow) * K + gc * 8;
    const short* gB = W + (size_t)(n0 + srow) * K + gc * 8;
    char* AsB = (char*)As;
    char* BsB = (char*)Bs;
    char* dstA = AsB + wave * 1024;
    char* dstB = BsB + wave * 1024;

    int aoff[4], boff[4], soff[2];
#pragma unroll
    for (int mi = 0; mi < 4; ++mi) aoff[mi] = (wr * 64 + mi * 16 + (l & 15)) * 128;
#pragma unroll
    for (int ni = 0; ni < 4; ++ni) boff[ni] = (wc * 64 + ni * 16 + (l & 15)) * 128;
#pragma unroll
    for (int kh = 0; kh < 2; ++kh) soff[kh] = ((kh * 4 + (l >> 4)) ^ (l & 7)) * 16;

    for (int kt = 0; kt < K; kt += 64) {
#pragma unroll
        for (int j = 0; j < 4; ++j) {
            load_lds16(gA + (size_t)j * 32 * K + kt, dstA + j * 4096);
            load_lds16(gB + (size_t)j * 32 * K + kt, dstB + j * 4096);
        }
        __syncthreads();
#pragma unroll
        for (int kh = 0; kh < 2; ++kh) {
            s16x8 af[4], bfr[4];
#pragma unroll
            for (int mi = 0; mi < 4; ++mi)
                af[mi] = *(const s16x8*)(AsB + aoff[mi] + soff[kh]);
#pragma unroll
            for (int ni = 0; ni < 4; ++ni)
                bfr[ni] = *(const s16x8*)(BsB + boff[ni] + soff[kh]);
#pragma unroll
            for (int mi = 0; mi < 4; ++mi)
#pragma unroll
                for (int ni = 0; ni < 4; ++ni)
                    acc[mi][ni] = __builtin_amdgcn_mfma_f32_16x16x32_bf16(
                        af[mi], bfr[ni], acc[mi][ni], 0, 0, 0);
        }
        __syncthreads();
    }

    const int colf = l & 15, rowf = (l >> 4) * 4;
#pragma unroll
    for (int mi = 0; mi < 4; ++mi)
#pragma unroll
        for (int ni = 0; ni < 4; ++ni) {
            const int n = n0 + wc * 64 + ni * 16 + colf;
            const float bv = bias[n];
#pragma unroll
            for (int r = 0; r < 4; ++r) {
                const int m = m0 + wr * 64 + mi * 16 + rowf + r;
                float v = acc[mi][ni][r] + bv;
                if (RELU) v = fmaxf(v, 0.f);
                if (OBF16) ((short*)Cv)[(size_t)m * N + n] = f2bf(v);
                else       ((float*)Cv)[(size_t)m * N + n] = v;
            }
        }
}

// ---------------- f32 -> bf16 conversion (optional elementwise mask) -------
__global__ void conv_bf16(const float* __restrict__ in, const float* __restrict__ mask,
                          short* __restrict__ out, int n4)
{
    int i = blockIdx.x * blockDim.x + threadIdx.x;
    if (i >= n4) return;
    float4 v = ((const float4*)in)[i];
    if (mask) {
        float4 m = ((const float4*)mask)[i];
        v.x *= m.x; v.y *= m.y; v.z *= m.z; v.w *= m.w;
    }
    short4 o;
    o.x = f2bf(v.x); o.y = f2bf(v.y); o.z = f2bf(v.z); o.w = f2bf(v.w);
    ((short4*)out)[i] = o;
}

// ---------------- f32 -> bf16 with K-padding (for GEMM1, 168 -> 192) -------
__global__ void padconv_bf16(const float* __restrict__ in, const float* __restrict__ mask,
                             short* __restrict__ out, int M, int Kin4, int Kout4)
{
    int idx = blockIdx.x * blockDim.x + threadIdx.x;
    if (idx >= M * Kout4) return;
    int m = idx / Kout4, k4 = idx % Kout4;
    float4 v = make_float4(0.f, 0.f, 0.f, 0.f);
    if (k4 < Kin4) {
        v = ((const float4*)in)[(size_t)m * Kin4 + k4];
        if (mask) {
            float4 mm = ((const float4*)mask)[(size_t)m * Kin4 + k4];
            v.x *= mm.x; v.y *= mm.y; v.z *= mm.z; v.w *= mm.w;
        }
    }
    short4 o;
    o.x = f2bf(v.x); o.y = f2bf(v.y); o.z = f2bf(v.z); o.w = f2bf(v.w);
    ((short4*)out)[(size_t)m * Kout4 + k4] = o;
}

// ---------------- combined LSTM biases -------------------------------------
__global__ void bias_sum_kernel(const float* __restrict__ bihf, const float* __restrict__ bhhf,
                                const float* __restrict__ bihb, const float* __restrict__ bhhb,
                                float* __restrict__ o)
{
    int i = blockIdx.x * blockDim.x + threadIdx.x;
    if (i < 2048)      o[i] = bihf[i] + bhhf[i];
    else if (i < 4096) o[i] = bihb[i - 2048] + bhhb[i - 2048];
}

// ---------------- one BiLSTM time step, single-exposure staging ------------
// grid = 128: dir = bid>>6, jg = bid&63 -> 8 gate-cols per block, all 4 gates.
// Per step: issue ALL 16 global_load_lds per wave (8 h-tiles + 8 w-tiles),
// ONE syncthreads, 32 MFMAs, gate math. c in global f32, h ping-pong bf16.
__global__ __launch_bounds__(256, 2)
void lstm_step2(int t,
                const float* __restrict__ xp,   // [2048][4096] f32 (fwd|bwd)
                const short* __restrict__ whb,  // [2][2048][512] bf16
                short* __restrict__ hbuf,       // [2][2][32*512] bf16
                float* __restrict__ cbuf,       // [2][32*512] f32
                short* __restrict__ y,          // [32][64][1024] bf16
                float* __restrict__ out)        // hidden/cell at t==63
{
    __shared__ short wT[8 * 32 * 64];    // 32 KB: 8 k-tiles x [32 rows][64 k]
    __shared__ short hT[8 * 32 * 64];    // 32 KB
    __shared__ float gbuf[4][32][9];     // 4.6 KB gate exchange

    const int bid = blockIdx.x;
    const int dir = bid >> 6;
    const int jg  = bid & 63;
    const int j0  = jg * 8;
    const int tid = threadIdx.x;
    const int l    = tid & 63;
    const int wave = tid >> 6;
    const int tt = dir ? (63 - t) : t;

    const short* whh = whb + (size_t)dir * 1048576;
    const short* hread  = hbuf + dir * 2 * 16384 + (t & 1) * 16384;
    short*       hwrite = hbuf + dir * 2 * 16384 + ((t + 1) & 1) * 16384;
    float*       cst    = cbuf + dir * 16384;

    char* wTB = (char*)wT;
    char* hTB = (char*)hT;

    // gate-math ownership: 1 output per thread
    const int gb = tid >> 3;          // batch 0..31
    const int gj = tid & 7;           // j-local 0..7
    const int j  = j0 + gj;

    // prefetch xp + c early (independent of h staging)
    const float* xpr = xp + ((size_t)(gb * 64 + tt)) * 4096 + dir * 2048 + j;
    const float xi = xpr[0], xf = xpr[512], xg = xpr[1024], xo = xpr[1536];
    float c_old = cst[gb * 512 + j];

    // ---- staging addresses: wave w covers local rows w*8 + (l>>3) ----
    const int rloc = wave * 8 + (l >> 3);         // 0..31
    const int gc   = (l & 7) ^ (rloc & 7);        // pre-swizzled k-chunk
    // w_hh: local row r -> gate (r>>3), col j0 + (r&7)
    const short* gW = whh + (size_t)((rloc >> 3) * 512 + j0 + (rloc & 7)) * 512 + gc * 8;
    // h: local row = batch
    const short* gH = hread + rloc * 512 + gc * 8;
    char* dstW = wTB + wave * 1024;
    char* dstH = hTB + wave * 1024;

    // issue ALL staging loads, single exposure
#pragma unroll
    for (int kt = 0; kt < 8; ++kt) {
        load_lds16(gH + kt * 64, dstH + kt * 4096);
        load_lds16(gW + kt * 64, dstW + kt * 4096);
    }

    // fragment offsets (swizzled read side); B rows for cols>=8 duplicate 0..7
    int soff[2];
    soff[0] = ((0 * 4 + (l >> 4)) ^ (l & 7)) * 16;
    soff[1] = ((1 * 4 + (l >> 4)) ^ (l & 7)) * 16;
    const int a0off = (l & 15) * 128;
    const int a1off = (16 + (l & 15)) * 128;
    const int bof   = (wave * 8 + (l & 7)) * 128;   // (l&15)&7 == l&7

    __syncthreads();   // compiler inserts vmcnt(0) before barrier

    // MFMA: gates[32 batches, 8 cols] for gate `wave`, K=512
    f32x4 acc0, acc1;
    acc0[0] = 0.f; acc0[1] = 0.f; acc0[2] = 0.f; acc0[3] = 0.f;
    acc1 = acc0;
#pragma unroll
    for (int kt = 0; kt < 8; ++kt) {
#pragma unroll
        for (int kh = 0; kh < 2; ++kh) {
            s16x8 bv = *(const s16x8*)(wTB + kt * 4096 + bof + soff[kh]);
            s16x8 a0 = *(const s16x8*)(hTB + kt * 4096 + a0off + soff[kh]);
            s16x8 a1 = *(const s16x8*)(hTB + kt * 4096 + a1off + soff[kh]);
            acc0 = __builtin_amdgcn_mfma_f32_16x16x32_bf16(a0, bv, acc0, 0, 0, 0);
            acc1 = __builtin_amdgcn_mfma_f32_16x16x32_bf16(a1, bv, acc1, 0, 0, 0);
        }
    }

    // scatter gates: wave w = gate w; C/D col = l&15 (valid < 8), row batches
    if ((l & 15) < 8) {
        const int sj = l & 15, r4 = (l >> 4) * 4;
#pragma unroll
        for (int r = 0; r < 4; ++r) {
            gbuf[wave][r4 + r][sj]      = acc0[r];
            gbuf[wave][16 + r4 + r][sj] = acc1[r];
        }
    }
    __syncthreads();

    // fused gate math: thread (gb, gj) owns one (batch, j)
    {
        float g_i = gbuf[0][gb][gj] + xi;
        float g_f = gbuf[1][gb][gj] + xf;
        float g_g = gbuf[2][gb][gj] + xg;
        float g_o = gbuf[3][gb][gj] + xo;
        float si = 1.f / (1.f + expf(-g_i));
        float sf = 1.f / (1.f + expf(-g_f));
        float so = 1.f / (1.f + expf(-g_o));
        float tg = tanhf(g_g);
        float c_new = sf * c_old + si * tg;
        float h_new = so * tanhf(c_new);

        cst[gb * 512 + j] = c_new;
        const short hb16 = f2bf(h_new);
        hwrite[gb * 512 + j] = hb16;
        y[((size_t)(gb * 64 + tt)) * 1024 + dir * 512 + j] = hb16;

        if (t == 63) {
            out[524288 + dir * 16384 + gb * 512 + j]         = h_new;
            out[524288 + 32768 + dir * 16384 + gb * 512 + j] = c_new;
        }
    }
}

// ---------------------------------------------------------------------------
extern "C" void kernel_launch(void* const* d_in, const int* in_sizes, int n_in,
                              void* d_out, int out_size, void* d_ws, size_t ws_size,
                              hipStream_t stream)
{
    const float* x     = (const float*)d_in[0];
    const float* w1    = (const float*)d_in[1];
    const float* b1    = (const float*)d_in[2];
    const float* mask1 = (const float*)d_in[3];
    const float* w2    = (const float*)d_in[4];
    const float* b2    = (const float*)d_in[5];
    const float* mask2 = (const float*)d_in[6];
    const float* wihf  = (const float*)d_in[7];
    const float* whhf  = (const float*)d_in[8];
    const float* bihf  = (const float*)d_in[9];
    const float* bhhf  = (const float*)d_in[10];
    const float* wihb  = (const float*)d_in[11];
    const float* whhb  = (const float*)d_in[12];
    const float* bihb  = (const float*)d_in[13];
    const float* bhhb  = (const float*)d_in[14];
    const float* wo1   = (const float*)d_in[15];
    const float* bo1   = (const float*)d_in[16];
    const float* wo2   = (const float*)d_in[17];
    const float* bo2   = (const float*)d_in[18];
    float* out = (float*)d_out;

    // ---- workspace regions (byte offsets), lifetime-based aliasing ----
    char* base = (char*)d_ws;
    short* wqb  = (short*)base;                       // later whb
    short* whb  = (short*)base;
    char*  Breg = base + 29360128;
    short* h2b  = (short*)Breg;
    short* xpad = (short*)Breg;                       // [2048][192] bf16
    short* w1mb = (short*)(Breg + 786432);            // [1792][192] bf16
    char*  Creg = base + 44040192;
    float* xp   = (float*)Creg;
    short* w2b  = (short*)Creg;
    char*  Dreg = base + 77594624;
    short* h1b  = (short*)Dreg;
    short* ybuf = (short*)Dreg;
    short* o1   = (short*)(Dreg + 4194304);
    short* wo1b = (short*)(Dreg + 5242880);
    short* wo2b = (short*)(Dreg + 5767168);
    char*  Ereg = base + 84934656;
    short* hbuf = (short*)Ereg;                       // 131072 B
    float* cbuf = (float*)(Ereg + 131072);            // 131072 B
    float* bsum = (float*)(Ereg + 262144);            // 16384 B

    hipMemsetAsync(Ereg, 0, 262144, stream);   // hbuf + cbuf zeros
    bias_sum_kernel<<<16, 256, 0, stream>>>(bihf, bhhf, bihb, bhhb, bsum);

    // weight / input conversions
    conv_bf16<<<6272, 256, 0, stream>>>(w2, mask2, w2b, 6422528 / 4);
    conv_bf16<<<7168, 256, 0, stream>>>(wihf, nullptr, wqb, 7340032 / 4);
    conv_bf16<<<7168, 256, 0, stream>>>(wihb, nullptr, wqb + 7340032, 7340032 / 4);
    padconv_bf16<<<384, 256, 0, stream>>>(x, nullptr, xpad, 2048, 42, 48);
    padconv_bf16<<<336, 256, 0, stream>>>(w1, mask1, w1mb, 1792, 42, 48);

    // GEMM1 (MFMA, K padded to 192)
    gemm_mfma<true, true><<<dim3(1792 / 128, 2048 / 128), 256, 0, stream>>>(
        xpad, w1mb, b1, h1b, 2048, 1792, 192);

    // GEMM2 (MFMA)
    gemm_mfma<true, true><<<dim3(3584 / 128, 2048 / 128), 256, 0, stream>>>(
        h1b, w2b, b2, h2b, 2048, 3584, 1792);

    // merged LSTM input projection: h2b @ [wihf;wihb]^T + bsum -> xp f32
    gemm_mfma<false, false><<<dim3(4096 / 128, 2048 / 128), 256, 0, stream>>>(
        h2b, wqb, bsum, xp, 2048, 4096, 3584);

    // recurrent weights to bf16 (aliases wqb -> after xproj)
    conv_bf16<<<1024, 256, 0, stream>>>(whhf, nullptr, whb, 1048576 / 4);
    conv_bf16<<<1024, 256, 0, stream>>>(whhb, nullptr, whb + 1048576, 1048576 / 4);
    // head weights to bf16 (alias h1b tail -> after GEMM2)
    conv_bf16<<<256, 256, 0, stream>>>(wo1, nullptr, wo1b, 262144 / 4);
    conv_bf16<<<64, 256, 0, stream>>>(wo2, nullptr, wo2b, 65536 / 4);

    // 64 sequential BiLSTM steps (single-exposure staging, 128 blocks)
    for (int t = 0; t < 64; ++t)
        lstm_step2<<<128, 256, 0, stream>>>(t, xp, whb, hbuf, cbuf, ybuf, out);

    // output head (MFMA)
    gemm_mfma<true, true><<<dim3(256 / 128, 2048 / 128), 256, 0, stream>>>(
        ybuf, wo1b, bo1, o1, 2048, 256, 1024);
    gemm_mfma<false, false><<<dim3(256 / 128, 2048 / 128), 256, 0, stream>>>(
        o1, wo2b, bo2, out, 2048, 256, 256);
}